// Round 3
// baseline (266.938 us; speedup 1.0000x reference)
//
#include <hip/hip_runtime.h>
#include <stdint.h>

// Problem geometry (B=32, C=384, H=W=56), float32 in/out.
#define TOTAL_N 38535168   // 32*384*56*56
#define HW_SZ   3136       // 56*56  (multiple of 8 -> 8 consecutive elems share a channel)
#define NCH     384

__device__ __forceinline__ uint32_t rotl32(uint32_t x, int r) {
  return (x << r) | (x >> (32 - r));
}

// ---------------------------------------------------------------------------
// JAX *partitionable* threefry path (default since JAX 0.4.30):
//   bits[i] = o0 ^ o1, (o0,o1) = threefry2x32(key=(0,42), counter=(hi(i)=0, lo(i)=i))
// 20 rounds, rotation schedule [13,15,26,6] / [17,29,16,24], standard key injections.
// ---------------------------------------------------------------------------
__device__ __forceinline__ uint32_t tf_bits(uint32_t i) {
  const uint32_t ks0 = 0u;
  const uint32_t ks1 = 42u;
  const uint32_t ks2 = 0x1BD11BDAu ^ 0u ^ 42u;  // 0x1BD11BF0

  uint32_t x0 = 0u + ks0;   // counter_hi + ks[0]
  uint32_t x1 = i + ks1;    // counter_lo + ks[1]

#define TF_R(r) { x0 += x1; x1 = rotl32(x1, (r)) ^ x0; }
  TF_R(13) TF_R(15) TF_R(26) TF_R(6)
  x0 += ks1; x1 += ks2 + 1u;
  TF_R(17) TF_R(29) TF_R(16) TF_R(24)
  x0 += ks2; x1 += ks0 + 2u;
  TF_R(13) TF_R(15) TF_R(26) TF_R(6)
  x0 += ks0; x1 += ks1 + 3u;
  TF_R(17) TF_R(29) TF_R(16) TF_R(24)
  x0 += ks1; x1 += ks2 + 4u;
  TF_R(13) TF_R(15) TF_R(26) TF_R(6)
  x0 += ks2; x1 += ks0 + 5u;
#undef TF_R

  return x0 ^ x1;  // 32-bit width combines the two output words by XOR
}

// bits -> uniform [0,1): exactly JAX's f32 path
__device__ __forceinline__ float bits_to_unit(uint32_t b) {
  uint32_t fb = (b >> 9) | 0x3f800000u;
  float f = __builtin_bit_cast(float, fb);
  return f - 1.0f;
}

// ---------------------------------------------------------------------------
// Prep: min/max over feature_importance[384] -> keep_prob[384] in workspace.
// Exact f32 op order (no FMA contraction) to match the numpy/XLA reference.
// ---------------------------------------------------------------------------
__global__ __launch_bounds__(64) void prep_keep_prob(
    const float* __restrict__ fi, float* __restrict__ keep) {
  int t = threadIdx.x;  // 0..63
  float mn = fi[t];
  float mx = mn;
  for (int c = t + 64; c < NCH; c += 64) {
    float v = fi[c];
    mn = fminf(mn, v);
    mx = fmaxf(mx, v);
  }
  for (int off = 1; off < 64; off <<= 1) {
    mn = fminf(mn, __shfl_xor(mn, off));
    mx = fmaxf(mx, __shfl_xor(mx, off));
  }
  float denom = __fsub_rn(mx, mn);
  for (int c = t; c < NCH; c += 64) {
    float scaled = __fdiv_rn(__fsub_rn(fi[c], mn), denom);
    float one_minus = __fsub_rn(1.0f, scaled);
    float rates = __fadd_rn(0.1f, __fmul_rn(0.4f, one_minus));
    keep[c] = __fsub_rn(1.0f, rates);
  }
}

// ---------------------------------------------------------------------------
// Main: 8 consecutive elements per thread (two float4 loads/stores).
// HW_SZ % 8 == 0 -> all 8 share one channel.
// ---------------------------------------------------------------------------
__global__ __launch_bounds__(256) void dropout_kernel(
    const float* __restrict__ x, const float* __restrict__ keep,
    float* __restrict__ out) {
  int tid = blockIdx.x * 256 + threadIdx.x;
  int i0 = tid << 3;
  if (i0 >= TOTAL_N) return;

  float kp = keep[(i0 / HW_SZ) % NCH];

  float4 xa = *reinterpret_cast<const float4*>(x + i0);
  float4 xb = *reinterpret_cast<const float4*>(x + i0 + 4);
  float4 oa, ob;

  oa.x = (bits_to_unit(tf_bits(i0 + 0)) < kp) ? xa.x : 0.0f;
  oa.y = (bits_to_unit(tf_bits(i0 + 1)) < kp) ? xa.y : 0.0f;
  oa.z = (bits_to_unit(tf_bits(i0 + 2)) < kp) ? xa.z : 0.0f;
  oa.w = (bits_to_unit(tf_bits(i0 + 3)) < kp) ? xa.w : 0.0f;
  ob.x = (bits_to_unit(tf_bits(i0 + 4)) < kp) ? xb.x : 0.0f;
  ob.y = (bits_to_unit(tf_bits(i0 + 5)) < kp) ? xb.y : 0.0f;
  ob.z = (bits_to_unit(tf_bits(i0 + 6)) < kp) ? xb.z : 0.0f;
  ob.w = (bits_to_unit(tf_bits(i0 + 7)) < kp) ? xb.w : 0.0f;

  *reinterpret_cast<float4*>(out + i0) = oa;
  *reinterpret_cast<float4*>(out + i0 + 4) = ob;
}

extern "C" void kernel_launch(void* const* d_in, const int* in_sizes, int n_in,
                              void* d_out, int out_size, void* d_ws, size_t ws_size,
                              hipStream_t stream) {
  const float* x = (const float*)d_in[0];
  const float* fi = (const float*)d_in[1];
  float* out = (float*)d_out;
  float* keep = (float*)d_ws;  // 384 floats of scratch

  prep_keep_prob<<<1, 64, 0, stream>>>(fi, keep);

  const int threads_total = TOTAL_N / 8;           // 4,816,896
  const int blocks = threads_total / 256;          // 18,816 (exact)
  dropout_kernel<<<blocks, 256, 0, stream>>>(x, keep, out);
}